// Round 1
// baseline (890.904 us; speedup 1.0000x reference)
//
#include <hip/hip_runtime.h>
#include <hip/hip_bf16.h>

// Problem constants
#define B_   2
#define H_   16
#define SQ_  2048
#define SK_  2048
#define D_   128

// Tiling
#define QT   128   // q rows per block
#define KT   64    // k cols per iteration
#define NITER (SK_/KT)

using bf16x8 = __attribute__((ext_vector_type(8))) __bf16;
using bf16x4 = __attribute__((ext_vector_type(4))) __bf16;
using f32x4  = __attribute__((ext_vector_type(4))) float;

#define MFMA16(a,b,c) __builtin_amdgcn_mfma_f32_16x16x32_bf16(a,b,c,0,0,0)

// LDS pitches in elements (bf16) / bytes (mask)
#define QK_PITCH 136   // Q/K tiles [row][d], 272 B rows (16B-aligned, bank-spread)
#define VT_PITCH 72    // V^T [d][k], 144 B rows
#define P_PITCH  72    // P [q][k], 144 B rows
#define M8_PITCH 72    // mask bytes [q][k], 72 B rows

#define KLDS_BYTES (KT  * QK_PITCH * 2)   // 17408
#define VT_BYTES   (D_  * VT_PITCH * 2)   // 18432
#define P_BYTES    (QT  * P_PITCH  * 2)   // 18432
#define M8_BYTES   (QT  * M8_PITCH)       // 9216
#define SMEM_BYTES (KLDS_BYTES + VT_BYTES + P_BYTES + M8_BYTES)  // 63488 < 64 KiB

__global__ __launch_bounds__(256, 2)
void attn_drop_kernel(const float* __restrict__ Q,
                      const float* __restrict__ K,
                      const float* __restrict__ V,
                      const int*   __restrict__ M,
                      float* __restrict__ Out)
{
    __shared__ __align__(16) char smem[SMEM_BYTES];
    __bf16*  Qs  = (__bf16*)smem;                            // prologue only (overlaps K+V)
    __bf16*  Ks  = (__bf16*)smem;                            // [KT][QK_PITCH]
    __bf16*  Vt  = (__bf16*)(smem + KLDS_BYTES);             // [D_][VT_PITCH]
    __bf16*  Ps  = (__bf16*)(smem + KLDS_BYTES + VT_BYTES);  // [QT][P_PITCH]
    unsigned char* Ms8 = (unsigned char*)(smem + KLDS_BYTES + VT_BYTES + P_BYTES); // [QT][M8_PITCH]

    const int tid  = threadIdx.x;
    const int wave = tid >> 6;
    const int lane = tid & 63;
    const int quad = lane >> 4;
    const int ln   = lane & 15;

    // XCD-aware bijective swizzle (512 blocks % 8 XCDs == 0):
    // XCD x gets orig ids [64x,64x+64) -> 4 whole heads per XCD, K/V L2-local.
    const int orig = ((blockIdx.x & 7) << 6) | (blockIdx.x >> 3);
    const int bh = orig >> 4;   // head index
    const int qb = orig & 15;   // q-block within head

    const float* qptr = Q + ((size_t)bh*SQ_ + (size_t)qb*QT) * D_;
    const float* kptr = K + (size_t)bh*SK_*D_;
    const float* vptr = V + (size_t)bh*SK_*D_;
    const int*   mptr = M + (size_t)bh*(size_t)SQ_*SK_ + (size_t)qb*QT*SK_;
    float*       optr = Out + ((size_t)bh*SQ_ + (size_t)qb*QT) * D_;

    const int c  = tid & 31;   // float4 column within a 128-wide row
    const int g  = tid >> 5;   // row group 0..7
    const int mc = tid & 15;   // int4 column within a 64-wide mask row
    const int mg = tid >> 4;   // mask row group 0..15

    // ---------------- T14 prefetch registers (tile kt+1 in flight across compute) ----
    float4 kpre[8], vpre[8];
    int4   mpre[8];

    auto load_tile = [&](int kt) {
        const float4* ks = (const float4*)(kptr + (size_t)kt*KT*D_);
        const float4* vs = (const float4*)(vptr + (size_t)kt*KT*D_);
        #pragma unroll
        for (int p = 0; p < 8; ++p) kpre[p] = ks[(g + 8*p)*32 + c];
        #pragma unroll
        for (int i = 0; i < 8; ++i) vpre[i] = vs[(8*g + i)*32 + c];
        const int* mrow = mptr + kt*KT + 4*mc;
        #pragma unroll
        for (int p = 0; p < 8; ++p)
            mpre[p] = *(const int4*)(mrow + (size_t)(mg + 16*p)*SK_);
    };

    auto write_tile = [&]() {
        // K tile [KT][128] -> bf16 LDS row-major
        #pragma unroll
        for (int p = 0; p < 8; ++p) {
            float4 v = kpre[p];
            bf16x4 h = { (__bf16)v.x, (__bf16)v.y, (__bf16)v.z, (__bf16)v.w };
            *(bf16x4*)&Ks[(g + 8*p)*QK_PITCH + 4*c] = h;
        }
        // V^T: thread holds 8 consecutive k rows at fixed d0=4c -> rows of V^T
        const float* ff = (const float*)vpre;
        #pragma unroll
        for (int j = 0; j < 4; ++j) {
            bf16x8 row = { (__bf16)ff[0*4+j], (__bf16)ff[1*4+j],
                           (__bf16)ff[2*4+j], (__bf16)ff[3*4+j],
                           (__bf16)ff[4*4+j], (__bf16)ff[5*4+j],
                           (__bf16)ff[6*4+j], (__bf16)ff[7*4+j] };
            *(bf16x8*)&Vt[(4*c + j)*VT_PITCH + 8*g] = row;  // (d0+j, k=8g..8g+7)
        }
        // mask int4 -> packed bytes (values are 0/1 by construction)
        #pragma unroll
        for (int p = 0; p < 8; ++p) {
            int4 m = mpre[p];
            unsigned pk = (unsigned)(m.x & 1) | ((unsigned)(m.y & 1) << 8)
                        | ((unsigned)(m.z & 1) << 16) | ((unsigned)(m.w & 1) << 24);
            *(unsigned*)&Ms8[(mg + 16*p)*M8_PITCH + 4*mc] = pk;
        }
    };

    // issue tile-0 loads first: latency hides under the whole Q prologue
    load_tile(0);

    // ---------------- Prologue: stage Q tile (128x128 f32 -> bf16 LDS) ----------------
    {
        const float4* src = (const float4*)qptr;   // [128][32] float4
        #pragma unroll
        for (int p = 0; p < 16; ++p) {
            int r = g + 8*p;
            float4 v = src[r*32 + c];
            bf16x4 h = { (__bf16)v.x, (__bf16)v.y, (__bf16)v.z, (__bf16)v.w };
            *(bf16x4*)&Qs[r*QK_PITCH + 4*c] = h;
        }
    }
    __syncthreads();

    // Q fragments register-resident for the whole K loop: [rowtile][dstep]
    bf16x8 qf[2][4];
    #pragma unroll
    for (int rt = 0; rt < 2; ++rt)
        #pragma unroll
        for (int s = 0; s < 4; ++s)
            qf[rt][s] = *(const bf16x8*)&Qs[(32*wave + 16*rt + ln)*QK_PITCH + 32*s + 8*quad];
    // no extra barrier: the loop's first __syncthreads covers the Qs-overwrite hazard

    f32x4 Oacc[2][8];
    #pragma unroll
    for (int rt = 0; rt < 2; ++rt)
        #pragma unroll
        for (int dt = 0; dt < 8; ++dt)
            Oacc[rt][dt] = (f32x4){0.f, 0.f, 0.f, 0.f};

    for (int kt = 0; kt < NITER; ++kt) {
        __syncthreads();        // A: all waves done reading LDS (qf at kt=0, prev tile else)
        write_tile();           // regs(tile kt) -> LDS (vmem already landed during prev compute)
        __syncthreads();        // B: tile kt visible (no outstanding vmem here -> cheap drain)
        if (kt + 1 < NITER) load_tile(kt + 1);   // in flight across the whole compute phase

        // ---- S = Q * K^T  (per wave: 32 q-rows x 64 k-cols)
        f32x4 S[2][4];
        #pragma unroll
        for (int rt = 0; rt < 2; ++rt)
            #pragma unroll
            for (int ct = 0; ct < 4; ++ct)
                S[rt][ct] = (f32x4){0.f, 0.f, 0.f, 0.f};

        __builtin_amdgcn_s_setprio(1);
        #pragma unroll
        for (int s = 0; s < 4; ++s) {
            #pragma unroll
            for (int ct = 0; ct < 4; ++ct) {
                bf16x8 kf = *(const bf16x8*)&Ks[(16*ct + ln)*QK_PITCH + 32*s + 8*quad];
                S[0][ct] = MFMA16(qf[0][s], kf, S[0][ct]);
                S[1][ct] = MFMA16(qf[1][s], kf, S[1][ct]);
            }
        }
        __builtin_amdgcn_s_setprio(0);

        // ---- dropout mask from LDS bytes + cast, write P to LDS (per-wave rows)
        #pragma unroll
        for (int rt = 0; rt < 2; ++rt) {
            #pragma unroll
            for (int ct = 0; ct < 4; ++ct) {
                int row0 = 32*wave + 16*rt + 4*quad;
                int col  = 16*ct + ln;
                #pragma unroll
                for (int r = 0; r < 4; ++r) {
                    float pv = Ms8[(row0 + r)*M8_PITCH + col] ? S[rt][ct][r] : 0.0f;
                    Ps[(row0 + r)*P_PITCH + col] = (__bf16)pv;   // scale folded into epilogue
                }
            }
        }
        // no barrier needed: each wave reads back only its own P rows (lgkmcnt handles RAW)

        // ---- O += P * V
        __builtin_amdgcn_s_setprio(1);
        #pragma unroll
        for (int ks = 0; ks < 2; ++ks) {
            bf16x8 pf0 = *(const bf16x8*)&Ps[(32*wave +      ln)*P_PITCH + 32*ks + 8*quad];
            bf16x8 pf1 = *(const bf16x8*)&Ps[(32*wave + 16 + ln)*P_PITCH + 32*ks + 8*quad];
            #pragma unroll
            for (int dt = 0; dt < 8; ++dt) {
                bf16x8 vf = *(const bf16x8*)&Vt[(16*dt + ln)*VT_PITCH + 32*ks + 8*quad];
                Oacc[0][dt] = MFMA16(pf0, vf, Oacc[0][dt]);
                Oacc[1][dt] = MFMA16(pf1, vf, Oacc[1][dt]);
            }
        }
        __builtin_amdgcn_s_setprio(0);
    }

    // ---- epilogue: apply folded scale 2*sqrt(D) and store fp32
    const float SCALE = 22.62741699796952f;  // 2 * sqrt(128) = 16*sqrt(2)
    #pragma unroll
    for (int rt = 0; rt < 2; ++rt) {
        #pragma unroll
        for (int dt = 0; dt < 8; ++dt) {
            int row0 = 32*wave + 16*rt + 4*quad;
            #pragma unroll
            for (int r = 0; r < 4; ++r)
                optr[(size_t)(row0 + r)*D_ + 16*dt + ln] = Oacc[rt][dt][r] * SCALE;
        }
    }
}

extern "C" void kernel_launch(void* const* d_in, const int* in_sizes, int n_in,
                              void* d_out, int out_size, void* d_ws, size_t ws_size,
                              hipStream_t stream) {
    (void)in_sizes; (void)n_in; (void)d_ws; (void)ws_size; (void)out_size;
    const float* Q = (const float*)d_in[0];
    const float* K = (const float*)d_in[1];
    const float* V = (const float*)d_in[2];
    const int*   M = (const int*)d_in[3];
    float* Out = (float*)d_out;

    dim3 grid(B_ * H_ * (SQ_ / QT));   // 32 * 16 = 512 blocks
    attn_drop_kernel<<<grid, 256, 0, stream>>>(Q, K, V, M, Out);
}